// Round 12
// baseline (321.810 us; speedup 1.0000x reference)
//
#include <hip/hip_runtime.h>
#include <hip/hip_bf16.h>
#include <stdint.h>

#define EMB 1024
#define HID 1024
#define NE 16
#define NTOK 8192
#define NSLOT (NTOK * 2)
#define BM 128
#define BN 128
#define BK 32

typedef __bf16 bf16;
typedef __bf16 bf16x8 __attribute__((ext_vector_type(8)));
typedef __bf16 bf16x4 __attribute__((ext_vector_type(4)));
typedef float f32x4 __attribute__((ext_vector_type(4)));

// async global->LDS, 16B per lane; LDS dest wave-uniform base + lane*16
#define GLOAD16(g, l)                                                        \
  __builtin_amdgcn_global_load_lds(                                          \
      (const __attribute__((address_space(1))) void*)(g),                    \
      (__attribute__((address_space(3))) void*)(l), 16, 0, 0)

#define VMW(N) asm volatile("s_waitcnt vmcnt(" #N ")" ::: "memory")
#define NOPS ((void)0)

// ========== 256x256 8-wave 2-phase/K-tile machinery (used by gemm2) ==========
#define PH_PRE                                                \
  __builtin_amdgcn_s_barrier();                               \
  __builtin_amdgcn_s_setprio(1)
#define PH_POST                                               \
  __builtin_amdgcn_s_setprio(0);                              \
  __builtin_amdgcn_s_barrier()

#define LDA2(D, M, CK) (*(const bf16x8*)&sh[((((D)<<1) + wm) << 13) + l15 * 64 + (CK) + (M) * 1024])
#define LDB2(D, N, CK) (*(const bf16x8*)&sh[32768 + ((((D)<<1) + (wn >> 1)) << 13) + ((wn & 1) << 12) + l15 * 64 + (CK) + (N) * 1024])

#define STG2_A(D, KO) do {                                                    \
    GLOAD16(agp00 + (KO), (char*)sh + ((((D)<<1) + 0) << 14) + wb);           \
    GLOAD16(agp01 + (KO), (char*)sh + ((((D)<<1) + 0) << 14) + 8192 + wb);    \
    GLOAD16(agp10 + (KO), (char*)sh + ((((D)<<1) + 1) << 14) + wb);           \
    GLOAD16(agp11 + (KO), (char*)sh + ((((D)<<1) + 1) << 14) + 8192 + wb);    \
  } while (0)
#define STG2_B(D, KO) do {                                                    \
    GLOAD16(bgp00 + (KO), (char*)sh + 65536 + ((((D)<<1) + 0) << 14) + wb);   \
    GLOAD16(bgp01 + (KO), (char*)sh + 65536 + ((((D)<<1) + 0) << 14) + 8192 + wb); \
    GLOAD16(bgp10 + (KO), (char*)sh + 65536 + ((((D)<<1) + 1) << 14) + wb);   \
    GLOAD16(bgp11 + (KO), (char*)sh + 65536 + ((((D)<<1) + 1) << 14) + 8192 + wb); \
  } while (0)

#define MM(MB, FA, FB) do {                                                   \
    _Pragma("unroll") for (int mq = 0; mq < 4; mq++)                          \
    _Pragma("unroll") for (int nq = 0; nq < 4; nq++)                          \
      acc[(MB) + mq][nq] = __builtin_amdgcn_mfma_f32_16x16x32_bf16(           \
          (FA)[mq], (FB)[nq], acc[(MB) + mq][nq], 0, 0, 0);                   \
  } while (0)

#define KTILE2(D, S2, W2) do {                                                \
    bf16x8 a0[8], b0[4];                                                      \
    _Pragma("unroll") for (int q = 0; q < 4; q++) b0[q] = LDB2(D, q, c0);     \
    _Pragma("unroll") for (int q = 0; q < 8; q++) a0[q] = LDA2(D, q, c0);     \
    PH_PRE; MM(0, a0, b0); MM(4, a0 + 4, b0); PH_POST;                        \
    bf16x8 a1[8], b1[4];                                                      \
    _Pragma("unroll") for (int q = 0; q < 4; q++) b1[q] = LDB2(D, q, c1);     \
    _Pragma("unroll") for (int q = 0; q < 8; q++) a1[q] = LDA2(D, q, c1);     \
    S2; W2;                                                                   \
    PH_PRE; MM(0, a1, b1); MM(4, a1 + 4, b1); PH_POST;                        \
  } while (0)

#define KLOOP2(NT2) do {                                                      \
    STG2_A(0, 0); STG2_B(0, 0); STG2_A(1, 64); STG2_B(1, 64);                 \
    VMW(8); __builtin_amdgcn_s_barrier();                                     \
    _Pragma("unroll 1") for (int i = 0; i < (NT2) - 1; i++) {                 \
      int k2 = (i * 2 + 2) * 64, k3 = (i * 2 + 3) * 64;                       \
      KTILE2(0, { STG2_B(0, k2); STG2_A(0, k2); }, VMW(8));                   \
      KTILE2(1, { STG2_B(1, k3); STG2_A(1, k3); }, VMW(8));                   \
    }                                                                         \
    KTILE2(0, NOPS, VMW(0));                                                  \
    KTILE2(1, NOPS, NOPS);                                                    \
  } while (0)

// ---------------- w_gate [1024][16] -> wgT [16][1024] (tiny, runs first) ----
__global__ void wgT_k(const float* __restrict__ wg, float* __restrict__ wgT) {
  int f = blockIdx.x * 256 + threadIdx.x;
  int d = f >> 4, e = f & 15;
  wgT[e * 1024 + d] = wg[f];
}

// ---------------- fused prep: weight transpose (blocks 0..6143, 2 tiles each)
//                  + router (blocks 6144..7167, 8 tokens each) ----------------
__launch_bounds__(512)
__global__ void prep_k(const float* __restrict__ w1, const float* __restrict__ w2,
                       const float* __restrict__ wcs, bf16* __restrict__ w1t,
                       bf16* __restrict__ w2t, bf16* __restrict__ wct,
                       const float* __restrict__ x, const float* __restrict__ wgT,
                       bf16* __restrict__ xb,
                       int* __restrict__ tokexp, float* __restrict__ tokgate) {
  __shared__ __align__(16) char lds[65536];   // union: wgs 64KB | 2 transpose tiles
  int bid = blockIdx.x;
  if (bid < 6144) {
    // ---- transpose branch: two 64x64 tile-units ----
    typedef bf16 TileT[64][68];
    TileT* tile = (TileT*)lds;
    int half = threadIdx.x >> 8, t = threadIdx.x & 255;
    int u = bid * 2 + half;
    int zz = u >> 8, t16 = u & 255;
    int n0 = (t16 & 15) << 6, k0 = (t16 >> 4) << 6;
    const float* s; bf16* d;
    if (zz < 16)      { s = w1;  d = w1t; }
    else if (zz < 32) { s = w2;  d = w2t; }
    else              { s = wcs; d = wct; }
    int z = zz & 15;
    s += (size_t)z << 20;
    d += (size_t)z << 20;

    int r = t >> 4, c4 = t & 15;
#pragma unroll
    for (int i = 0; i < 4; i++) {
      int row = r + (i << 4);
      float4 v = *(const float4*)&s[(size_t)(k0 + row) * 1024 + n0 + (c4 << 2)];
      bf16x4 o;
      o[0] = (bf16)v.x; o[1] = (bf16)v.y; o[2] = (bf16)v.z; o[3] = (bf16)v.w;
      *(bf16x4*)&tile[half][row][c4 << 2] = o;
    }
    __syncthreads();

    int r8 = t >> 3, ch = t & 7;
#pragma unroll
    for (int i = 0; i < 2; i++) {
      int on = r8 + (i << 5);
      bf16x8 v;
#pragma unroll
      for (int j = 0; j < 8; j++) v[j] = tile[half][(ch << 3) + j][on];
      *(bf16x8*)&d[(size_t)(n0 + on) * 1024 + k0 + (ch << 3)] = v;
    }
  } else {
    // ---- router branch: 8 tokens, LDS-staged wgT, fused x->bf16 ----
    float* wgs = (float*)lds;
    for (int i = threadIdx.x; i < 4096; i += 512)
      ((float4*)wgs)[i] = ((const float4*)wgT)[i];
    __syncthreads();

    int tok = (bid - 6144) * 8 + (threadIdx.x >> 6);
    int lane = threadIdx.x & 63;
    const float* xr = x + (size_t)tok * EMB;

    float acc[NE];
#pragma unroll
    for (int e = 0; e < NE; e++) acc[e] = 0.f;

#pragma unroll
    for (int c = 0; c < 4; c++) {
      float4 xv = ((const float4*)xr)[c * 64 + lane];
      int dbase = c * 256 + lane * 4;
      bf16x4 o;
      o[0] = (bf16)xv.x; o[1] = (bf16)xv.y; o[2] = (bf16)xv.z; o[3] = (bf16)xv.w;
      *(bf16x4*)(xb + (size_t)tok * EMB + dbase) = o;
#pragma unroll
      for (int e = 0; e < NE; e++) {
        float4 wv = *(const float4*)&wgs[e * 1024 + dbase];
        acc[e] += xv.x * wv.x + xv.y * wv.y + xv.z * wv.z + xv.w * wv.w;
      }
    }
#pragma unroll
    for (int e = 0; e < NE; e++) {
#pragma unroll
      for (int s2 = 32; s2 > 0; s2 >>= 1) acc[e] += __shfl_xor(acc[e], s2);
    }
    if (lane == 0) {
      float m = acc[0];
#pragma unroll
      for (int e = 1; e < NE; e++) m = fmaxf(m, acc[e]);
      float p[NE]; float sum = 0.f;
#pragma unroll
      for (int e = 0; e < NE; e++) { p[e] = __expf(acc[e] - m); sum += p[e]; }
      float inv = 1.f / sum;
#pragma unroll
      for (int e = 0; e < NE; e++) p[e] *= inv;
      int i1 = 0;
#pragma unroll
      for (int e = 1; e < NE; e++) if (p[e] > p[i1]) i1 = e;
      int i2 = (i1 == 0) ? 1 : 0;
#pragma unroll
      for (int e = 0; e < NE; e++) if (e != i1 && p[e] > p[i2]) i2 = e;
      tokexp[2 * tok] = i1; tokexp[2 * tok + 1] = i2;
      tokgate[2 * tok] = p[i1]; tokgate[2 * tok + 1] = p[i2];
    }
  }
}

// ---------------- per-block expert histogram ----------------
__global__ void hist_k(const int* __restrict__ tokexp, int* __restrict__ blockcnt) {
  __shared__ int h[NE];
  int tid = threadIdx.x;
  if (tid < NE) h[tid] = 0;
  __syncthreads();
  int e = tokexp[blockIdx.x * 256 + tid];
  atomicAdd(&h[e], 1);
  __syncthreads();
  if (tid < NE) blockcnt[blockIdx.x * NE + tid] = h[tid];
}

// ---------------- scan ----------------
__global__ void scan_k(const int* __restrict__ blockcnt, int* __restrict__ cnt,
                       int* __restrict__ eoff, int* __restrict__ blockoff) {
  __shared__ int scnt[NE], soff[NE];
  int t = threadIdx.x;
  if (t < NE) {
    int s = 0;
    for (int b = 0; b < 64; b++) s += blockcnt[b * NE + t];
    scnt[t] = s;
    cnt[t] = s;
  }
  __syncthreads();
  if (t == 0) {
    int s = 0;
    for (int e = 0; e < NE; e++) { soff[e] = s; eoff[e] = s; s += scnt[e]; }
  }
  __syncthreads();
  if (t < NE) {
    int run = soff[t];
    for (int b = 0; b < 64; b++) { blockoff[b * NE + t] = run; run += blockcnt[b * NE + t]; }
  }
}

// ---------------- slot -> compact row, ballot ranking (+ inverse map) ------
__global__ void assign_k(const int* __restrict__ tokexp, const float* __restrict__ tokgate,
                         const int* __restrict__ blockoff, int* __restrict__ rowtok,
                         float* __restrict__ rowgate, int* __restrict__ posof) {
  __shared__ int wavecnt[4][NE];
  __shared__ int waveoff[4][NE];
  int tid = threadIdx.x;
  int w = tid >> 6, lane = tid & 63;
  int s = blockIdx.x * 256 + tid;
  int e = tokexp[s];
  int rank = 0;
  unsigned long long ltmask = (1ull << lane) - 1ull;
#pragma unroll
  for (int ee = 0; ee < NE; ee++) {
    unsigned long long bal = __ballot(e == ee);
    if (e == ee) rank = __popcll(bal & ltmask);
    if (lane == ee) wavecnt[w][ee] = __popcll(bal);
  }
  __syncthreads();
  if (tid < 64) {
    int ww = tid >> 4, ee = tid & 15;
    int off = 0;
    for (int p = 0; p < ww; p++) off += wavecnt[p][ee];
    waveoff[ww][ee] = off;
  }
  __syncthreads();
  int pos = blockoff[blockIdx.x * NE + e] + waveoff[w][e] + rank;
  rowtok[pos] = s >> 1;
  rowgate[pos] = tokgate[s];
  posof[s] = pos;
}

// ---------------- GEMM1 (R6-proven): H = silu(X@W1)*(X@W2), 128x128, dbuf ---
__launch_bounds__(256, 3)
__global__ void gemm1_k(const bf16* __restrict__ xb, const bf16* __restrict__ w1t,
                        const bf16* __restrict__ w2t, const int* __restrict__ cnt,
                        const int* __restrict__ eoff, const int* __restrict__ rowtok,
                        bf16* __restrict__ H) {
  int id = blockIdx.x;
  int nid = (id & 7) * 256 + (id >> 3);       // XCD chunk swizzle (2048 % 8 == 0)
  int e = nid >> 7;                           // 128 blocks/expert = 16 mt x 8 nt
  int rem = nid & 127;
  int m0 = (rem >> 3) * BM;                   // 16 m-tiles: n_e <= 2048 (30 sigma)
  int n0 = (rem & 7) * BN;
  int n_e = cnt[e];
  if (m0 >= n_e) return;
  int base = eoff[e];

  __shared__ __align__(16) bf16 sA[2][BM * BK];
  __shared__ __align__(16) bf16 sB1[2][BN * BK];
  __shared__ __align__(16) bf16 sB2[2][BN * BK];

  int tid = threadIdx.x;
  int lane = tid & 63;
  int w = tid >> 6;
  int wr = (w >> 1) << 6;
  int wc = (w & 1) << 6;

  int srow = tid >> 2;                        // 0..63
  int kc = (((tid & 3) ^ ((tid >> 3) & 3)) << 3);   // swizzled k-chunk (bf16 elems)

  const bf16 *ag0, *ag1;
  {
    int gi0 = base + m0 + srow;
    int gi1 = base + m0 + 64 + srow;
    gi0 = gi0 < NSLOT ? gi0 : NSLOT - 1;      // clamp: garbage rows masked at store
    gi1 = gi1 < NSLOT ? gi1 : NSLOT - 1;
    ag0 = xb + (size_t)rowtok[gi0] * EMB + kc;
    ag1 = xb + (size_t)rowtok[gi1] * EMB + kc;
  }
  const bf16* b1g = w1t + ((size_t)e * HID + n0 + srow) * EMB + kc;
  const bf16* b2g = w2t + ((size_t)e * HID + n0 + srow) * EMB + kc;
  const size_t B64 = (size_t)64 * EMB;

  char* lA  = (char*)sA  + w * 1024;
  char* lB1 = (char*)sB1 + w * 1024;
  char* lB2 = (char*)sB2 + w * 1024;

#define G1STAGE(k0, b) do {                                                  \
    char* _A = lA + (b) * 8192; char* _B1 = lB1 + (b) * 8192;                \
    char* _B2 = lB2 + (b) * 8192;                                            \
    GLOAD16(ag0 + (k0), _A);                                                 \
    GLOAD16(ag1 + (k0), _A + 4096);                                          \
    GLOAD16(b1g + (k0), _B1);                                                \
    GLOAD16(b1g + B64 + (k0), _B1 + 4096);                                   \
    GLOAD16(b2g + (k0), _B2);                                                \
    GLOAD16(b2g + B64 + (k0), _B2 + 4096);                                   \
  } while (0)

  f32x4 acc1[4][4] = {};
  f32x4 acc2[4][4] = {};

  int chr = ((lane >> 4) ^ ((lane >> 1) & 3)) << 3;   // swizzled read chunk
  int ra = (wr + (lane & 15)) * BK + chr;
  int rb = (wc + (lane & 15)) * BK + chr;

  G1STAGE(0, 0);                               // prologue
  for (int t = 0; t < EMB / BK; t++) {
    int cur = t & 1;
    if (t < EMB / BK - 1) {
      G1STAGE((t + 1) * BK, cur ^ 1);          // keep next tile's 6 loads in flight
      VMW(6);
    } else {
      VMW(0);
    }
    __builtin_amdgcn_s_barrier();

    bf16x8 af[4], b1f[4], b2f[4];
#pragma unroll
    for (int m = 0; m < 4; m++) af[m] = *(const bf16x8*)&sA[cur][ra + m * 16 * BK];
#pragma unroll
    for (int n = 0; n < 4; n++) {
      b1f[n] = *(const bf16x8*)&sB1[cur][rb + n * 16 * BK];
      b2f[n] = *(const bf16x8*)&sB2[cur][rb + n * 16 * BK];
    }
#pragma unroll
    for (int m = 0; m < 4; m++)
#pragma unroll
      for (int n = 0; n < 4; n++) {
        acc1[m][n] = __builtin_amdgcn_mfma_f32_16x16x32_bf16(af[m], b1f[n], acc1[m][n], 0, 0, 0);
        acc2[m][n] = __builtin_amdgcn_mfma_f32_16x16x32_bf16(af[m], b2f[n], acc2[m][n], 0, 0, 0);
      }
    __builtin_amdgcn_s_barrier();
  }
#undef G1STAGE

  // epilogue: silu(c1)*c2 -> bf16 H.  D frag: col=lane&15, row=4*(lane>>4)+b
  int rf = wr + ((lane >> 4) << 2);
  int cf = n0 + wc + (lane & 15);
#pragma unroll
  for (int m = 0; m < 4; m++) {
#pragma unroll
    for (int n = 0; n < 4; n++) {
#pragma unroll
      for (int b = 0; b < 4; b++) {
        int gr = m0 + rf + m * 16 + b;
        if (gr < n_e) {
          float c1 = acc1[m][n][b];
          float c2 = acc2[m][n][b];
          float h = c1 * c2 / (1.f + __expf(-c1));
          H[(size_t)(base + gr) * HID + cf + n * 16] = (bf16)h;
        }
      }
    }
  }
}

// ---------------- GEMM2: Ob[pos] = gate * (H @ Wc), 256x256 KLOOP2 ---------
__launch_bounds__(512, 2)
__global__ void gemm2_k(const bf16* __restrict__ Hb, const bf16* __restrict__ wct,
                        const int* __restrict__ cnt, const int* __restrict__ eoff,
                        const float* __restrict__ rowgate, bf16* __restrict__ Ob) {
  int id = blockIdx.x;
  int nid = (id & 7) * 128 + (id >> 3);       // XCD swizzle (1024 % 8 == 0)
  int e = nid >> 6, rem = nid & 63;           // 16 mt x 4 nt
  int m0 = (rem >> 2) << 8;
  int n0 = (rem & 3) << 8;
  int n_e = cnt[e];
  if (m0 >= n_e) return;
  int base0 = eoff[e];
  extern __shared__ bf16 sh[];

  int tid = threadIdx.x, lane = tid & 63, w = tid >> 6;
  int wm = w >> 2, wn = w & 3;
  int l15 = lane & 15, l4 = lane >> 4, r7 = l15 & 7;
  int c0 = ((l4 ^ r7) << 3), c1 = (((4 + l4) ^ r7) << 3);
  int srow = tid >> 3;
  int kg8 = (((tid & 7) ^ (srow & 7)) << 3);
  int wb = w << 10;

  const bf16 *agp00, *agp01, *agp10, *agp11, *bgp00, *bgp01, *bgp10, *bgp11;
  {
    int g0 = base0 + m0 + srow;        g0 = g0 < NSLOT ? g0 : NSLOT - 1;
    int g1 = base0 + m0 + 64 + srow;   g1 = g1 < NSLOT ? g1 : NSLOT - 1;
    int g2 = base0 + m0 + 128 + srow;  g2 = g2 < NSLOT ? g2 : NSLOT - 1;
    int g3 = base0 + m0 + 192 + srow;  g3 = g3 < NSLOT ? g3 : NSLOT - 1;
    agp00 = Hb + ((size_t)g0 << 10) + kg8;
    agp01 = Hb + ((size_t)g1 << 10) + kg8;
    agp10 = Hb + ((size_t)g2 << 10) + kg8;
    agp11 = Hb + ((size_t)g3 << 10) + kg8;
    const bf16* wce = wct + ((size_t)e << 20);
    bgp00 = wce + ((size_t)(n0 + srow) << 10) + kg8;
    bgp01 = wce + ((size_t)(n0 + 64 + srow) << 10) + kg8;
    bgp10 = wce + ((size_t)(n0 + 128 + srow) << 10) + kg8;
    bgp11 = wce + ((size_t)(n0 + 192 + srow) << 10) + kg8;
  }

  f32x4 acc[8][4] = {};
  KLOOP2(8);   // K = 1024 = 16 tiles

  int rb0 = m0 + (wm << 7) + (l4 << 2);
  int cb0 = n0 + (wn << 6) + l15;
#pragma unroll
  for (int m = 0; m < 8; m++)
#pragma unroll
    for (int b = 0; b < 4; b++) {
      int gr = rb0 + m * 16 + b;
      if (gr < n_e) {
        int idx = base0 + gr;
        float g = rowgate[idx];
        bf16* orow = Ob + ((size_t)idx << 10) + cb0;
#pragma unroll
        for (int n = 0; n < 4; n++)
          orow[n * 16] = (bf16)(g * acc[m][n][b]);
      }
    }
}

// ---------------- combine: out[t] = Ob[posof[2t]] + Ob[posof[2t+1]] --------
__global__ void combine_k(const bf16* __restrict__ Ob, const int* __restrict__ posof,
                          float* __restrict__ out) {
  int t = blockIdx.x;
  int c = threadIdx.x << 2;
  int p1 = posof[2 * t], p2 = posof[2 * t + 1];
  bf16x4 a = *(const bf16x4*)&Ob[((size_t)p1 << 10) + c];
  bf16x4 b = *(const bf16x4*)&Ob[((size_t)p2 << 10) + c];
  float4 o;
  o.x = (float)a[0] + (float)b[0];
  o.y = (float)a[1] + (float)b[1];
  o.z = (float)a[2] + (float)b[2];
  o.w = (float)a[3] + (float)b[3];
  *(float4*)&out[((size_t)t << 10) + c] = o;
}

extern "C" void kernel_launch(void* const* d_in, const int* in_sizes, int n_in,
                              void* d_out, int out_size, void* d_ws, size_t ws_size,
                              hipStream_t stream) {
  const float* x  = (const float*)d_in[0];
  const float* wg = (const float*)d_in[1];
  const float* w1 = (const float*)d_in[2];
  const float* w2 = (const float*)d_in[3];
  const float* wc = (const float*)d_in[4];
  float* out = (float*)d_out;

  const size_t WELEM = (size_t)NE << 20;
  bf16* w1t  = (bf16*)d_ws;                        // [E][HID][EMB] bf16
  bf16* w2t  = w1t + WELEM;                        // [E][HID][EMB]
  bf16* wct  = w2t + WELEM;                        // [E][EMB][HID]
  bf16* xb   = wct + WELEM;                        // [NTOK][1024]
  bf16* Hb   = xb + ((size_t)NTOK << 10);          // [NSLOT][1024]
  int* cnt      = (int*)(Hb + ((size_t)NSLOT << 10));
  int* eoff     = cnt + 16;
  int* blockcnt = eoff + 16;                       // [64][16]
  int* blockoff = blockcnt + 64 * 16;              // [64][16]
  int* tokexp   = blockoff + 64 * 16;              // [NSLOT]
  float* tokgate = (float*)(tokexp + NSLOT);
  int* rowtok    = (int*)(tokgate + NSLOT);
  float* rowgate = (float*)(rowtok + NSLOT);
  int* posof     = (int*)(rowgate + NSLOT);        // [NSLOT]
  float* wgT     = (float*)(posof + NSLOT);        // [16][1024] fp32
  // Ob aliases w1t: w1t/w2t dead after gemm1 (same-stream kernels serialize)
  bf16* Ob = w1t;                                  // [NSLOT][1024] bf16 (= 32 MB)

  hipFuncSetAttribute((const void*)gemm2_k, hipFuncAttributeMaxDynamicSharedMemorySize, 131072);

  wgT_k<<<64, 256, 0, stream>>>(wg, wgT);
  prep_k<<<7168, 512, 0, stream>>>(w1, w2, wc, w1t, w2t, wct, x, wgT, xb, tokexp, tokgate);
  hist_k<<<NSLOT / 256, 256, 0, stream>>>(tokexp, blockcnt);
  scan_k<<<1, 64, 0, stream>>>(blockcnt, cnt, eoff, blockoff);
  assign_k<<<NSLOT / 256, 256, 0, stream>>>(tokexp, tokgate, blockoff, rowtok, rowgate, posof);
  gemm1_k<<<2048, 256, 0, stream>>>(xb, w1t, w2t, cnt, eoff, rowtok, Hb);
  gemm2_k<<<1024, 512, 131072, stream>>>(Hb, wct, cnt, eoff, rowgate, Ob);
  combine_k<<<NTOK, 256, 0, stream>>>(Ob, posof, out);
}

// Round 13
// 273.042 us; speedup vs baseline: 1.1786x; 1.1786x over previous
//
#include <hip/hip_runtime.h>
#include <hip/hip_bf16.h>
#include <stdint.h>

#define EMB 1024
#define HID 1024
#define NE 16
#define NTOK 8192
#define NSLOT (NTOK * 2)
#define BM 128
#define BN 128
#define BK 32

typedef __bf16 bf16;
typedef __bf16 bf16x8 __attribute__((ext_vector_type(8)));
typedef __bf16 bf16x4 __attribute__((ext_vector_type(4)));
typedef float f32x4 __attribute__((ext_vector_type(4)));

// async global->LDS, 16B per lane; LDS dest wave-uniform base + lane*16
#define GLOAD16(g, l)                                                        \
  __builtin_amdgcn_global_load_lds(                                          \
      (const __attribute__((address_space(1))) void*)(g),                    \
      (__attribute__((address_space(3))) void*)(l), 16, 0, 0)

#define VMW(N) asm volatile("s_waitcnt vmcnt(" #N ")" ::: "memory")
#define NOPS ((void)0)

// ========== 256x256 8-wave 2-phase/K-tile machinery (used by gemm2) ==========
#define PH_PRE                                                \
  __builtin_amdgcn_s_barrier();                               \
  __builtin_amdgcn_s_setprio(1)
#define PH_POST                                               \
  __builtin_amdgcn_s_setprio(0);                              \
  __builtin_amdgcn_s_barrier()

#define LDA2(D, M, CK) (*(const bf16x8*)&sh[((((D)<<1) + wm) << 13) + l15 * 64 + (CK) + (M) * 1024])
#define LDB2(D, N, CK) (*(const bf16x8*)&sh[32768 + ((((D)<<1) + (wn >> 1)) << 13) + ((wn & 1) << 12) + l15 * 64 + (CK) + (N) * 1024])

#define STG2_A(D, KO) do {                                                    \
    GLOAD16(agp00 + (KO), (char*)sh + ((((D)<<1) + 0) << 14) + wb);           \
    GLOAD16(agp01 + (KO), (char*)sh + ((((D)<<1) + 0) << 14) + 8192 + wb);    \
    GLOAD16(agp10 + (KO), (char*)sh + ((((D)<<1) + 1) << 14) + wb);           \
    GLOAD16(agp11 + (KO), (char*)sh + ((((D)<<1) + 1) << 14) + 8192 + wb);    \
  } while (0)
#define STG2_B(D, KO) do {                                                    \
    GLOAD16(bgp00 + (KO), (char*)sh + 65536 + ((((D)<<1) + 0) << 14) + wb);   \
    GLOAD16(bgp01 + (KO), (char*)sh + 65536 + ((((D)<<1) + 0) << 14) + 8192 + wb); \
    GLOAD16(bgp10 + (KO), (char*)sh + 65536 + ((((D)<<1) + 1) << 14) + wb);   \
    GLOAD16(bgp11 + (KO), (char*)sh + 65536 + ((((D)<<1) + 1) << 14) + 8192 + wb); \
  } while (0)

#define MM(MB, FA, FB) do {                                                   \
    _Pragma("unroll") for (int mq = 0; mq < 4; mq++)                          \
    _Pragma("unroll") for (int nq = 0; nq < 4; nq++)                          \
      acc[(MB) + mq][nq] = __builtin_amdgcn_mfma_f32_16x16x32_bf16(           \
          (FA)[mq], (FB)[nq], acc[(MB) + mq][nq], 0, 0, 0);                   \
  } while (0)

#define KTILE2(D, S2, W2) do {                                                \
    bf16x8 a0[8], b0[4];                                                      \
    _Pragma("unroll") for (int q = 0; q < 4; q++) b0[q] = LDB2(D, q, c0);     \
    _Pragma("unroll") for (int q = 0; q < 8; q++) a0[q] = LDA2(D, q, c0);     \
    PH_PRE; MM(0, a0, b0); MM(4, a0 + 4, b0); PH_POST;                        \
    bf16x8 a1[8], b1[4];                                                      \
    _Pragma("unroll") for (int q = 0; q < 4; q++) b1[q] = LDB2(D, q, c1);     \
    _Pragma("unroll") for (int q = 0; q < 8; q++) a1[q] = LDA2(D, q, c1);     \
    S2; W2;                                                                   \
    PH_PRE; MM(0, a1, b1); MM(4, a1 + 4, b1); PH_POST;                        \
  } while (0)

#define KLOOP2(NT2) do {                                                      \
    STG2_A(0, 0); STG2_B(0, 0); STG2_A(1, 64); STG2_B(1, 64);                 \
    VMW(8); __builtin_amdgcn_s_barrier();                                     \
    _Pragma("unroll 1") for (int i = 0; i < (NT2) - 1; i++) {                 \
      int k2 = (i * 2 + 2) * 64, k3 = (i * 2 + 3) * 64;                       \
      KTILE2(0, { STG2_B(0, k2); STG2_A(0, k2); }, VMW(8));                   \
      KTILE2(1, { STG2_B(1, k3); STG2_A(1, k3); }, VMW(8));                   \
    }                                                                         \
    KTILE2(0, NOPS, VMW(0));                                                  \
    KTILE2(1, NOPS, NOPS);                                                    \
  } while (0)

// ---------------- w_gate [1024][16] -> wgT [16][1024] (tiny, runs first) ----
__global__ void wgT_k(const float* __restrict__ wg, float* __restrict__ wgT) {
  int f = blockIdx.x * 256 + threadIdx.x;
  int d = f >> 4, e = f & 15;
  wgT[e * 1024 + d] = wg[f];
}

// ---------------- fused prep: weight transpose (blocks 0..6143, 2 tiles each)
//                  + router (blocks 6144..7167, 8 tokens each) ----------------
__launch_bounds__(512)
__global__ void prep_k(const float* __restrict__ w1, const float* __restrict__ w2,
                       const float* __restrict__ wcs, bf16* __restrict__ w1t,
                       bf16* __restrict__ w2t, bf16* __restrict__ wct,
                       const float* __restrict__ x, const float* __restrict__ wgT,
                       bf16* __restrict__ xb,
                       int* __restrict__ tokexp, float* __restrict__ tokgate) {
  __shared__ __align__(16) char lds[65536];   // union: wgs 64KB | 2 transpose tiles
  int bid = blockIdx.x;
  if (bid < 6144) {
    // ---- transpose branch: two 64x64 tile-units ----
    typedef bf16 TileT[64][68];
    TileT* tile = (TileT*)lds;
    int half = threadIdx.x >> 8, t = threadIdx.x & 255;
    int u = bid * 2 + half;
    int zz = u >> 8, t16 = u & 255;
    int n0 = (t16 & 15) << 6, k0 = (t16 >> 4) << 6;
    const float* s; bf16* d;
    if (zz < 16)      { s = w1;  d = w1t; }
    else if (zz < 32) { s = w2;  d = w2t; }
    else              { s = wcs; d = wct; }
    int z = zz & 15;
    s += (size_t)z << 20;
    d += (size_t)z << 20;

    int r = t >> 4, c4 = t & 15;
#pragma unroll
    for (int i = 0; i < 4; i++) {
      int row = r + (i << 4);
      float4 v = *(const float4*)&s[(size_t)(k0 + row) * 1024 + n0 + (c4 << 2)];
      bf16x4 o;
      o[0] = (bf16)v.x; o[1] = (bf16)v.y; o[2] = (bf16)v.z; o[3] = (bf16)v.w;
      *(bf16x4*)&tile[half][row][c4 << 2] = o;
    }
    __syncthreads();

    int r8 = t >> 3, ch = t & 7;
#pragma unroll
    for (int i = 0; i < 2; i++) {
      int on = r8 + (i << 5);
      bf16x8 v;
#pragma unroll
      for (int j = 0; j < 8; j++) v[j] = tile[half][(ch << 3) + j][on];
      *(bf16x8*)&d[(size_t)(n0 + on) * 1024 + k0 + (ch << 3)] = v;
    }
  } else {
    // ---- router branch: 8 tokens, LDS-staged wgT, fused x->bf16 ----
    float* wgs = (float*)lds;
    for (int i = threadIdx.x; i < 4096; i += 512)
      ((float4*)wgs)[i] = ((const float4*)wgT)[i];
    __syncthreads();

    int tok = (bid - 6144) * 8 + (threadIdx.x >> 6);
    int lane = threadIdx.x & 63;
    const float* xr = x + (size_t)tok * EMB;

    float acc[NE];
#pragma unroll
    for (int e = 0; e < NE; e++) acc[e] = 0.f;

#pragma unroll
    for (int c = 0; c < 4; c++) {
      float4 xv = ((const float4*)xr)[c * 64 + lane];
      int dbase = c * 256 + lane * 4;
      bf16x4 o;
      o[0] = (bf16)xv.x; o[1] = (bf16)xv.y; o[2] = (bf16)xv.z; o[3] = (bf16)xv.w;
      *(bf16x4*)(xb + (size_t)tok * EMB + dbase) = o;
#pragma unroll
      for (int e = 0; e < NE; e++) {
        float4 wv = *(const float4*)&wgs[e * 1024 + dbase];
        acc[e] += xv.x * wv.x + xv.y * wv.y + xv.z * wv.z + xv.w * wv.w;
      }
    }
#pragma unroll
    for (int e = 0; e < NE; e++) {
#pragma unroll
      for (int s2 = 32; s2 > 0; s2 >>= 1) acc[e] += __shfl_xor(acc[e], s2);
    }
    if (lane == 0) {
      float m = acc[0];
#pragma unroll
      for (int e = 1; e < NE; e++) m = fmaxf(m, acc[e]);
      float p[NE]; float sum = 0.f;
#pragma unroll
      for (int e = 0; e < NE; e++) { p[e] = __expf(acc[e] - m); sum += p[e]; }
      float inv = 1.f / sum;
#pragma unroll
      for (int e = 0; e < NE; e++) p[e] *= inv;
      int i1 = 0;
#pragma unroll
      for (int e = 1; e < NE; e++) if (p[e] > p[i1]) i1 = e;
      int i2 = (i1 == 0) ? 1 : 0;
#pragma unroll
      for (int e = 0; e < NE; e++) if (e != i1 && p[e] > p[i2]) i2 = e;
      tokexp[2 * tok] = i1; tokexp[2 * tok + 1] = i2;
      tokgate[2 * tok] = p[i1]; tokgate[2 * tok + 1] = p[i2];
    }
  }
}

// ---------------- per-block expert histogram ----------------
__global__ void hist_k(const int* __restrict__ tokexp, int* __restrict__ blockcnt) {
  __shared__ int h[NE];
  int tid = threadIdx.x;
  if (tid < NE) h[tid] = 0;
  __syncthreads();
  int e = tokexp[blockIdx.x * 256 + tid];
  atomicAdd(&h[e], 1);
  __syncthreads();
  if (tid < NE) blockcnt[blockIdx.x * NE + tid] = h[tid];
}

// ---------------- scan ----------------
__global__ void scan_k(const int* __restrict__ blockcnt, int* __restrict__ cnt,
                       int* __restrict__ eoff, int* __restrict__ blockoff) {
  __shared__ int scnt[NE], soff[NE];
  int t = threadIdx.x;
  if (t < NE) {
    int s = 0;
    for (int b = 0; b < 64; b++) s += blockcnt[b * NE + t];
    scnt[t] = s;
    cnt[t] = s;
  }
  __syncthreads();
  if (t == 0) {
    int s = 0;
    for (int e = 0; e < NE; e++) { soff[e] = s; eoff[e] = s; s += scnt[e]; }
  }
  __syncthreads();
  if (t < NE) {
    int run = soff[t];
    for (int b = 0; b < 64; b++) { blockoff[b * NE + t] = run; run += blockcnt[b * NE + t]; }
  }
}

// ---------------- slot -> compact row, ballot ranking (+ inverse map) ------
__global__ void assign_k(const int* __restrict__ tokexp, const float* __restrict__ tokgate,
                         const int* __restrict__ blockoff, int* __restrict__ rowtok,
                         float* __restrict__ rowgate, int* __restrict__ posof) {
  __shared__ int wavecnt[4][NE];
  __shared__ int waveoff[4][NE];
  int tid = threadIdx.x;
  int w = tid >> 6, lane = tid & 63;
  int s = blockIdx.x * 256 + tid;
  int e = tokexp[s];
  int rank = 0;
  unsigned long long ltmask = (1ull << lane) - 1ull;
#pragma unroll
  for (int ee = 0; ee < NE; ee++) {
    unsigned long long bal = __ballot(e == ee);
    if (e == ee) rank = __popcll(bal & ltmask);
    if (lane == ee) wavecnt[w][ee] = __popcll(bal);
  }
  __syncthreads();
  if (tid < 64) {
    int ww = tid >> 4, ee = tid & 15;
    int off = 0;
    for (int p = 0; p < ww; p++) off += wavecnt[p][ee];
    waveoff[ww][ee] = off;
  }
  __syncthreads();
  int pos = blockoff[blockIdx.x * NE + e] + waveoff[w][e] + rank;
  rowtok[pos] = s >> 1;
  rowgate[pos] = tokgate[s];
  posof[s] = pos;
}

// ---------------- GEMM1 (R6-proven): H = silu(X@W1)*(X@W2), 128x128, dbuf ---
__launch_bounds__(256, 2)
__global__ void gemm1_k(const bf16* __restrict__ xb, const bf16* __restrict__ w1t,
                        const bf16* __restrict__ w2t, const int* __restrict__ cnt,
                        const int* __restrict__ eoff, const int* __restrict__ rowtok,
                        bf16* __restrict__ H) {
  int id = blockIdx.x;
  int nid = (id & 7) * 256 + (id >> 3);       // XCD chunk swizzle (2048 % 8 == 0)
  int e = nid >> 7;                           // 128 blocks/expert = 16 mt x 8 nt
  int rem = nid & 127;
  int m0 = (rem >> 3) * BM;                   // 16 m-tiles: n_e <= 2048 (30 sigma)
  int n0 = (rem & 7) * BN;
  int n_e = cnt[e];
  if (m0 >= n_e) return;
  int base = eoff[e];

  __shared__ __align__(16) bf16 sA[2][BM * BK];
  __shared__ __align__(16) bf16 sB1[2][BN * BK];
  __shared__ __align__(16) bf16 sB2[2][BN * BK];

  int tid = threadIdx.x;
  int lane = tid & 63;
  int w = tid >> 6;
  int wr = (w >> 1) << 6;
  int wc = (w & 1) << 6;

  int srow = tid >> 2;                        // 0..63
  int kc = (((tid & 3) ^ ((tid >> 3) & 3)) << 3);   // swizzled k-chunk (bf16 elems)

  const bf16 *ag0, *ag1;
  {
    int gi0 = base + m0 + srow;
    int gi1 = base + m0 + 64 + srow;
    gi0 = gi0 < NSLOT ? gi0 : NSLOT - 1;      // clamp: garbage rows masked at store
    gi1 = gi1 < NSLOT ? gi1 : NSLOT - 1;
    ag0 = xb + (size_t)rowtok[gi0] * EMB + kc;
    ag1 = xb + (size_t)rowtok[gi1] * EMB + kc;
  }
  const bf16* b1g = w1t + ((size_t)e * HID + n0 + srow) * EMB + kc;
  const bf16* b2g = w2t + ((size_t)e * HID + n0 + srow) * EMB + kc;
  const size_t B64 = (size_t)64 * EMB;

  char* lA  = (char*)sA  + w * 1024;
  char* lB1 = (char*)sB1 + w * 1024;
  char* lB2 = (char*)sB2 + w * 1024;

#define G1STAGE(k0, b) do {                                                  \
    char* _A = lA + (b) * 8192; char* _B1 = lB1 + (b) * 8192;                \
    char* _B2 = lB2 + (b) * 8192;                                            \
    GLOAD16(ag0 + (k0), _A);                                                 \
    GLOAD16(ag1 + (k0), _A + 4096);                                          \
    GLOAD16(b1g + (k0), _B1);                                                \
    GLOAD16(b1g + B64 + (k0), _B1 + 4096);                                   \
    GLOAD16(b2g + (k0), _B2);                                                \
    GLOAD16(b2g + B64 + (k0), _B2 + 4096);                                   \
  } while (0)

  f32x4 acc1[4][4] = {};
  f32x4 acc2[4][4] = {};

  int chr = ((lane >> 4) ^ ((lane >> 1) & 3)) << 3;   // swizzled read chunk
  int ra = (wr + (lane & 15)) * BK + chr;
  int rb = (wc + (lane & 15)) * BK + chr;

  G1STAGE(0, 0);                               // prologue
  for (int t = 0; t < EMB / BK; t++) {
    int cur = t & 1;
    if (t < EMB / BK - 1) {
      G1STAGE((t + 1) * BK, cur ^ 1);          // keep next tile's 6 loads in flight
      VMW(6);
    } else {
      VMW(0);
    }
    __builtin_amdgcn_s_barrier();

    bf16x8 af[4], b1f[4], b2f[4];
#pragma unroll
    for (int m = 0; m < 4; m++) af[m] = *(const bf16x8*)&sA[cur][ra + m * 16 * BK];
#pragma unroll
    for (int n = 0; n < 4; n++) {
      b1f[n] = *(const bf16x8*)&sB1[cur][rb + n * 16 * BK];
      b2f[n] = *(const bf16x8*)&sB2[cur][rb + n * 16 * BK];
    }
#pragma unroll
    for (int m = 0; m < 4; m++)
#pragma unroll
      for (int n = 0; n < 4; n++) {
        acc1[m][n] = __builtin_amdgcn_mfma_f32_16x16x32_bf16(af[m], b1f[n], acc1[m][n], 0, 0, 0);
        acc2[m][n] = __builtin_amdgcn_mfma_f32_16x16x32_bf16(af[m], b2f[n], acc2[m][n], 0, 0, 0);
      }
    __builtin_amdgcn_s_barrier();
  }
#undef G1STAGE

  // epilogue: silu(c1)*c2 -> bf16 H.  D frag: col=lane&15, row=4*(lane>>4)+b
  int rf = wr + ((lane >> 4) << 2);
  int cf = n0 + wc + (lane & 15);
#pragma unroll
  for (int m = 0; m < 4; m++) {
#pragma unroll
    for (int n = 0; n < 4; n++) {
#pragma unroll
      for (int b = 0; b < 4; b++) {
        int gr = m0 + rf + m * 16 + b;
        if (gr < n_e) {
          float c1 = acc1[m][n][b];
          float c2 = acc2[m][n][b];
          float h = c1 * c2 / (1.f + __expf(-c1));
          H[(size_t)(base + gr) * HID + cf + n * 16] = (bf16)h;
        }
      }
    }
  }
}

// ---------------- GEMM2: Ob[pos] = gate * (H @ Wc), 256x256 KLOOP2 ---------
__launch_bounds__(512, 2)
__global__ void gemm2_k(const bf16* __restrict__ Hb, const bf16* __restrict__ wct,
                        const int* __restrict__ cnt, const int* __restrict__ eoff,
                        const float* __restrict__ rowgate, bf16* __restrict__ Ob) {
  int id = blockIdx.x;
  int nid = (id & 7) * 128 + (id >> 3);       // XCD swizzle (1024 % 8 == 0)
  int e = nid >> 6, rem = nid & 63;           // 16 mt x 4 nt
  int m0 = (rem >> 2) << 8;
  int n0 = (rem & 3) << 8;
  int n_e = cnt[e];
  if (m0 >= n_e) return;
  int base0 = eoff[e];
  extern __shared__ bf16 sh[];

  int tid = threadIdx.x, lane = tid & 63, w = tid >> 6;
  int wm = w >> 2, wn = w & 3;
  int l15 = lane & 15, l4 = lane >> 4, r7 = l15 & 7;
  int c0 = ((l4 ^ r7) << 3), c1 = (((4 + l4) ^ r7) << 3);
  int srow = tid >> 3;
  int kg8 = (((tid & 7) ^ (srow & 7)) << 3);
  int wb = w << 10;

  const bf16 *agp00, *agp01, *agp10, *agp11, *bgp00, *bgp01, *bgp10, *bgp11;
  {
    int g0 = base0 + m0 + srow;        g0 = g0 < NSLOT ? g0 : NSLOT - 1;
    int g1 = base0 + m0 + 64 + srow;   g1 = g1 < NSLOT ? g1 : NSLOT - 1;
    int g2 = base0 + m0 + 128 + srow;  g2 = g2 < NSLOT ? g2 : NSLOT - 1;
    int g3 = base0 + m0 + 192 + srow;  g3 = g3 < NSLOT ? g3 : NSLOT - 1;
    agp00 = Hb + ((size_t)g0 << 10) + kg8;
    agp01 = Hb + ((size_t)g1 << 10) + kg8;
    agp10 = Hb + ((size_t)g2 << 10) + kg8;
    agp11 = Hb + ((size_t)g3 << 10) + kg8;
    const bf16* wce = wct + ((size_t)e << 20);
    bgp00 = wce + ((size_t)(n0 + srow) << 10) + kg8;
    bgp01 = wce + ((size_t)(n0 + 64 + srow) << 10) + kg8;
    bgp10 = wce + ((size_t)(n0 + 128 + srow) << 10) + kg8;
    bgp11 = wce + ((size_t)(n0 + 192 + srow) << 10) + kg8;
  }

  f32x4 acc[8][4] = {};
  KLOOP2(8);   // K = 1024 = 16 tiles

  int rb0 = m0 + (wm << 7) + (l4 << 2);
  int cb0 = n0 + (wn << 6) + l15;
#pragma unroll
  for (int m = 0; m < 8; m++)
#pragma unroll
    for (int b = 0; b < 4; b++) {
      int gr = rb0 + m * 16 + b;
      if (gr < n_e) {
        int idx = base0 + gr;
        float g = rowgate[idx];
        bf16* orow = Ob + ((size_t)idx << 10) + cb0;
#pragma unroll
        for (int n = 0; n < 4; n++)
          orow[n * 16] = (bf16)(g * acc[m][n][b]);
      }
    }
}

// ---------------- combine: out[t] = Ob[posof[2t]] + Ob[posof[2t+1]] --------
__global__ void combine_k(const bf16* __restrict__ Ob, const int* __restrict__ posof,
                          float* __restrict__ out) {
  int t = blockIdx.x;
  int c = threadIdx.x << 2;
  int p1 = posof[2 * t], p2 = posof[2 * t + 1];
  bf16x4 a = *(const bf16x4*)&Ob[((size_t)p1 << 10) + c];
  bf16x4 b = *(const bf16x4*)&Ob[((size_t)p2 << 10) + c];
  float4 o;
  o.x = (float)a[0] + (float)b[0];
  o.y = (float)a[1] + (float)b[1];
  o.z = (float)a[2] + (float)b[2];
  o.w = (float)a[3] + (float)b[3];
  *(float4*)&out[((size_t)t << 10) + c] = o;
}

extern "C" void kernel_launch(void* const* d_in, const int* in_sizes, int n_in,
                              void* d_out, int out_size, void* d_ws, size_t ws_size,
                              hipStream_t stream) {
  const float* x  = (const float*)d_in[0];
  const float* wg = (const float*)d_in[1];
  const float* w1 = (const float*)d_in[2];
  const float* w2 = (const float*)d_in[3];
  const float* wc = (const float*)d_in[4];
  float* out = (float*)d_out;

  const size_t WELEM = (size_t)NE << 20;
  bf16* w1t  = (bf16*)d_ws;                        // [E][HID][EMB] bf16
  bf16* w2t  = w1t + WELEM;                        // [E][HID][EMB]
  bf16* wct  = w2t + WELEM;                        // [E][EMB][HID]
  bf16* xb   = wct + WELEM;                        // [NTOK][1024]
  bf16* Hb   = xb + ((size_t)NTOK << 10);          // [NSLOT][1024]
  int* cnt      = (int*)(Hb + ((size_t)NSLOT << 10));
  int* eoff     = cnt + 16;
  int* blockcnt = eoff + 16;                       // [64][16]
  int* blockoff = blockcnt + 64 * 16;              // [64][16]
  int* tokexp   = blockoff + 64 * 16;              // [NSLOT]
  float* tokgate = (float*)(tokexp + NSLOT);
  int* rowtok    = (int*)(tokgate + NSLOT);
  float* rowgate = (float*)(rowtok + NSLOT);
  int* posof     = (int*)(rowgate + NSLOT);        // [NSLOT]
  float* wgT     = (float*)(posof + NSLOT);        // [16][1024] fp32
  // Ob aliases w1t: w1t/w2t dead after gemm1 (same-stream kernels serialize)
  bf16* Ob = w1t;                                  // [NSLOT][1024] bf16 (= 32 MB)

  hipFuncSetAttribute((const void*)gemm2_k, hipFuncAttributeMaxDynamicSharedMemorySize, 131072);

  wgT_k<<<64, 256, 0, stream>>>(wg, wgT);
  prep_k<<<7168, 512, 0, stream>>>(w1, w2, wc, w1t, w2t, wct, x, wgT, xb, tokexp, tokgate);
  hist_k<<<NSLOT / 256, 256, 0, stream>>>(tokexp, blockcnt);
  scan_k<<<1, 64, 0, stream>>>(blockcnt, cnt, eoff, blockoff);
  assign_k<<<NSLOT / 256, 256, 0, stream>>>(tokexp, tokgate, blockoff, rowtok, rowgate, posof);
  gemm1_k<<<2048, 256, 0, stream>>>(xb, w1t, w2t, cnt, eoff, rowtok, Hb);
  gemm2_k<<<1024, 512, 131072, stream>>>(Hb, wct, cnt, eoff, rowgate, Ob);
  combine_k<<<NTOK, 256, 0, stream>>>(Ob, posof, out);
}

// Round 14
// 267.164 us; speedup vs baseline: 1.2045x; 1.0220x over previous
//
#include <hip/hip_runtime.h>
#include <hip/hip_bf16.h>
#include <stdint.h>

#define EMB 1024
#define HID 1024
#define NE 16
#define NTOK 8192
#define NSLOT (NTOK * 2)
#define BM 128
#define BN 128
#define BK 32

typedef __bf16 bf16;
typedef __bf16 bf16x8 __attribute__((ext_vector_type(8)));
typedef __bf16 bf16x4 __attribute__((ext_vector_type(4)));
typedef float f32x4 __attribute__((ext_vector_type(4)));

// async global->LDS, 16B per lane; LDS dest wave-uniform base + lane*16
#define GLOAD16(g, l)                                                        \
  __builtin_amdgcn_global_load_lds(                                          \
      (const __attribute__((address_space(1))) void*)(g),                    \
      (__attribute__((address_space(3))) void*)(l), 16, 0, 0)

#define VMW(N) asm volatile("s_waitcnt vmcnt(" #N ")" ::: "memory")

// ---------------- w_gate [1024][16] -> wgT [16][1024] (tiny, runs first) ----
__global__ void wgT_k(const float* __restrict__ wg, float* __restrict__ wgT) {
  int f = blockIdx.x * 256 + threadIdx.x;
  int d = f >> 4, e = f & 15;
  wgT[e * 1024 + d] = wg[f];
}

// ---------------- fused prep: weight transpose (blocks 0..6143, 2 tiles each)
//                  + router (blocks 6144..7167, 8 tokens each) ----------------
__launch_bounds__(512)
__global__ void prep_k(const float* __restrict__ w1, const float* __restrict__ w2,
                       const float* __restrict__ wcs, bf16* __restrict__ w1t,
                       bf16* __restrict__ w2t, bf16* __restrict__ wct,
                       const float* __restrict__ x, const float* __restrict__ wgT,
                       bf16* __restrict__ xb,
                       int* __restrict__ tokexp, float* __restrict__ tokgate) {
  __shared__ __align__(16) char lds[65536];   // union: wgs 64KB | 2 transpose tiles
  int bid = blockIdx.x;
  if (bid < 6144) {
    // ---- transpose branch: two 64x64 tile-units ----
    typedef bf16 TileT[64][68];
    TileT* tile = (TileT*)lds;
    int half = threadIdx.x >> 8, t = threadIdx.x & 255;
    int u = bid * 2 + half;
    int zz = u >> 8, t16 = u & 255;
    int n0 = (t16 & 15) << 6, k0 = (t16 >> 4) << 6;
    const float* s; bf16* d;
    if (zz < 16)      { s = w1;  d = w1t; }
    else if (zz < 32) { s = w2;  d = w2t; }
    else              { s = wcs; d = wct; }
    int z = zz & 15;
    s += (size_t)z << 20;
    d += (size_t)z << 20;

    int r = t >> 4, c4 = t & 15;
#pragma unroll
    for (int i = 0; i < 4; i++) {
      int row = r + (i << 4);
      float4 v = *(const float4*)&s[(size_t)(k0 + row) * 1024 + n0 + (c4 << 2)];
      bf16x4 o;
      o[0] = (bf16)v.x; o[1] = (bf16)v.y; o[2] = (bf16)v.z; o[3] = (bf16)v.w;
      *(bf16x4*)&tile[half][row][c4 << 2] = o;
    }
    __syncthreads();

    int r8 = t >> 3, ch = t & 7;
#pragma unroll
    for (int i = 0; i < 2; i++) {
      int on = r8 + (i << 5);
      bf16x8 v;
#pragma unroll
      for (int j = 0; j < 8; j++) v[j] = tile[half][(ch << 3) + j][on];
      *(bf16x8*)&d[(size_t)(n0 + on) * 1024 + k0 + (ch << 3)] = v;
    }
  } else {
    // ---- router branch: 8 tokens, LDS-staged wgT, fused x->bf16 ----
    float* wgs = (float*)lds;
    for (int i = threadIdx.x; i < 4096; i += 512)
      ((float4*)wgs)[i] = ((const float4*)wgT)[i];
    __syncthreads();

    int tok = (bid - 6144) * 8 + (threadIdx.x >> 6);
    int lane = threadIdx.x & 63;
    const float* xr = x + (size_t)tok * EMB;

    float acc[NE];
#pragma unroll
    for (int e = 0; e < NE; e++) acc[e] = 0.f;

#pragma unroll
    for (int c = 0; c < 4; c++) {
      float4 xv = ((const float4*)xr)[c * 64 + lane];
      int dbase = c * 256 + lane * 4;
      bf16x4 o;
      o[0] = (bf16)xv.x; o[1] = (bf16)xv.y; o[2] = (bf16)xv.z; o[3] = (bf16)xv.w;
      *(bf16x4*)(xb + (size_t)tok * EMB + dbase) = o;
#pragma unroll
      for (int e = 0; e < NE; e++) {
        float4 wv = *(const float4*)&wgs[e * 1024 + dbase];
        acc[e] += xv.x * wv.x + xv.y * wv.y + xv.z * wv.z + xv.w * wv.w;
      }
    }
#pragma unroll
    for (int e = 0; e < NE; e++) {
#pragma unroll
      for (int s2 = 32; s2 > 0; s2 >>= 1) acc[e] += __shfl_xor(acc[e], s2);
    }
    if (lane == 0) {
      float m = acc[0];
#pragma unroll
      for (int e = 1; e < NE; e++) m = fmaxf(m, acc[e]);
      float p[NE]; float sum = 0.f;
#pragma unroll
      for (int e = 0; e < NE; e++) { p[e] = __expf(acc[e] - m); sum += p[e]; }
      float inv = 1.f / sum;
#pragma unroll
      for (int e = 0; e < NE; e++) p[e] *= inv;
      int i1 = 0;
#pragma unroll
      for (int e = 1; e < NE; e++) if (p[e] > p[i1]) i1 = e;
      int i2 = (i1 == 0) ? 1 : 0;
#pragma unroll
      for (int e = 0; e < NE; e++) if (e != i1 && p[e] > p[i2]) i2 = e;
      tokexp[2 * tok] = i1; tokexp[2 * tok + 1] = i2;
      tokgate[2 * tok] = p[i1]; tokgate[2 * tok + 1] = p[i2];
    }
  }
}

// ---------------- per-block expert histogram ----------------
__global__ void hist_k(const int* __restrict__ tokexp, int* __restrict__ blockcnt) {
  __shared__ int h[NE];
  int tid = threadIdx.x;
  if (tid < NE) h[tid] = 0;
  __syncthreads();
  int e = tokexp[blockIdx.x * 256 + tid];
  atomicAdd(&h[e], 1);
  __syncthreads();
  if (tid < NE) blockcnt[blockIdx.x * NE + tid] = h[tid];
}

// ---------------- scan ----------------
__global__ void scan_k(const int* __restrict__ blockcnt, int* __restrict__ cnt,
                       int* __restrict__ eoff, int* __restrict__ blockoff) {
  __shared__ int scnt[NE], soff[NE];
  int t = threadIdx.x;
  if (t < NE) {
    int s = 0;
    for (int b = 0; b < 64; b++) s += blockcnt[b * NE + t];
    scnt[t] = s;
    cnt[t] = s;
  }
  __syncthreads();
  if (t == 0) {
    int s = 0;
    for (int e = 0; e < NE; e++) { soff[e] = s; eoff[e] = s; s += scnt[e]; }
  }
  __syncthreads();
  if (t < NE) {
    int run = soff[t];
    for (int b = 0; b < 64; b++) { blockoff[b * NE + t] = run; run += blockcnt[b * NE + t]; }
  }
}

// ---------------- slot -> compact row, ballot ranking (+ inverse map) ------
__global__ void assign_k(const int* __restrict__ tokexp, const float* __restrict__ tokgate,
                         const int* __restrict__ blockoff, int* __restrict__ rowtok,
                         float* __restrict__ rowgate, int* __restrict__ posof) {
  __shared__ int wavecnt[4][NE];
  __shared__ int waveoff[4][NE];
  int tid = threadIdx.x;
  int w = tid >> 6, lane = tid & 63;
  int s = blockIdx.x * 256 + tid;
  int e = tokexp[s];
  int rank = 0;
  unsigned long long ltmask = (1ull << lane) - 1ull;
#pragma unroll
  for (int ee = 0; ee < NE; ee++) {
    unsigned long long bal = __ballot(e == ee);
    if (e == ee) rank = __popcll(bal & ltmask);
    if (lane == ee) wavecnt[w][ee] = __popcll(bal);
  }
  __syncthreads();
  if (tid < 64) {
    int ww = tid >> 4, ee = tid & 15;
    int off = 0;
    for (int p = 0; p < ww; p++) off += wavecnt[p][ee];
    waveoff[ww][ee] = off;
  }
  __syncthreads();
  int pos = blockoff[blockIdx.x * NE + e] + waveoff[w][e] + rank;
  rowtok[pos] = s >> 1;
  rowgate[pos] = tokgate[s];
  posof[s] = pos;
}

// ---------------- GEMM1 (R6-proven, FROZEN): H = silu(X@W1)*(X@W2) ---------
__launch_bounds__(256, 2)
__global__ void gemm1_k(const bf16* __restrict__ xb, const bf16* __restrict__ w1t,
                        const bf16* __restrict__ w2t, const int* __restrict__ cnt,
                        const int* __restrict__ eoff, const int* __restrict__ rowtok,
                        bf16* __restrict__ H) {
  int id = blockIdx.x;
  int nid = (id & 7) * 256 + (id >> 3);       // XCD chunk swizzle (2048 % 8 == 0)
  int e = nid >> 7;                           // 128 blocks/expert = 16 mt x 8 nt
  int rem = nid & 127;
  int m0 = (rem >> 3) * BM;                   // 16 m-tiles: n_e <= 2048 (30 sigma)
  int n0 = (rem & 7) * BN;
  int n_e = cnt[e];
  if (m0 >= n_e) return;
  int base = eoff[e];

  __shared__ __align__(16) bf16 sA[2][BM * BK];
  __shared__ __align__(16) bf16 sB1[2][BN * BK];
  __shared__ __align__(16) bf16 sB2[2][BN * BK];

  int tid = threadIdx.x;
  int lane = tid & 63;
  int w = tid >> 6;
  int wr = (w >> 1) << 6;
  int wc = (w & 1) << 6;

  int srow = tid >> 2;                        // 0..63
  int kc = (((tid & 3) ^ ((tid >> 3) & 3)) << 3);   // swizzled k-chunk (bf16 elems)

  const bf16 *ag0, *ag1;
  {
    int gi0 = base + m0 + srow;
    int gi1 = base + m0 + 64 + srow;
    gi0 = gi0 < NSLOT ? gi0 : NSLOT - 1;      // clamp: garbage rows masked at store
    gi1 = gi1 < NSLOT ? gi1 : NSLOT - 1;
    ag0 = xb + (size_t)rowtok[gi0] * EMB + kc;
    ag1 = xb + (size_t)rowtok[gi1] * EMB + kc;
  }
  const bf16* b1g = w1t + ((size_t)e * HID + n0 + srow) * EMB + kc;
  const bf16* b2g = w2t + ((size_t)e * HID + n0 + srow) * EMB + kc;
  const size_t B64 = (size_t)64 * EMB;

  char* lA  = (char*)sA  + w * 1024;
  char* lB1 = (char*)sB1 + w * 1024;
  char* lB2 = (char*)sB2 + w * 1024;

#define G1STAGE(k0, b) do {                                                  \
    char* _A = lA + (b) * 8192; char* _B1 = lB1 + (b) * 8192;                \
    char* _B2 = lB2 + (b) * 8192;                                            \
    GLOAD16(ag0 + (k0), _A);                                                 \
    GLOAD16(ag1 + (k0), _A + 4096);                                          \
    GLOAD16(b1g + (k0), _B1);                                                \
    GLOAD16(b1g + B64 + (k0), _B1 + 4096);                                   \
    GLOAD16(b2g + (k0), _B2);                                                \
    GLOAD16(b2g + B64 + (k0), _B2 + 4096);                                   \
  } while (0)

  f32x4 acc1[4][4] = {};
  f32x4 acc2[4][4] = {};

  int chr = ((lane >> 4) ^ ((lane >> 1) & 3)) << 3;   // swizzled read chunk
  int ra = (wr + (lane & 15)) * BK + chr;
  int rb = (wc + (lane & 15)) * BK + chr;

  G1STAGE(0, 0);                               // prologue
  for (int t = 0; t < EMB / BK; t++) {
    int cur = t & 1;
    if (t < EMB / BK - 1) {
      G1STAGE((t + 1) * BK, cur ^ 1);          // keep next tile's 6 loads in flight
      VMW(6);
    } else {
      VMW(0);
    }
    __builtin_amdgcn_s_barrier();

    bf16x8 af[4], b1f[4], b2f[4];
#pragma unroll
    for (int m = 0; m < 4; m++) af[m] = *(const bf16x8*)&sA[cur][ra + m * 16 * BK];
#pragma unroll
    for (int n = 0; n < 4; n++) {
      b1f[n] = *(const bf16x8*)&sB1[cur][rb + n * 16 * BK];
      b2f[n] = *(const bf16x8*)&sB2[cur][rb + n * 16 * BK];
    }
#pragma unroll
    for (int m = 0; m < 4; m++)
#pragma unroll
      for (int n = 0; n < 4; n++) {
        acc1[m][n] = __builtin_amdgcn_mfma_f32_16x16x32_bf16(af[m], b1f[n], acc1[m][n], 0, 0, 0);
        acc2[m][n] = __builtin_amdgcn_mfma_f32_16x16x32_bf16(af[m], b2f[n], acc2[m][n], 0, 0, 0);
      }
    __builtin_amdgcn_s_barrier();
  }
#undef G1STAGE

  // epilogue: silu(c1)*c2 -> bf16 H.  D frag: col=lane&15, row=4*(lane>>4)+b
  int rf = wr + ((lane >> 4) << 2);
  int cf = n0 + wc + (lane & 15);
#pragma unroll
  for (int m = 0; m < 4; m++) {
#pragma unroll
    for (int n = 0; n < 4; n++) {
#pragma unroll
      for (int b = 0; b < 4; b++) {
        int gr = m0 + rf + m * 16 + b;
        if (gr < n_e) {
          float c1 = acc1[m][n][b];
          float c2 = acc2[m][n][b];
          float h = c1 * c2 / (1.f + __expf(-c1));
          H[(size_t)(base + gr) * HID + cf + n * 16] = (bf16)h;
        }
      }
    }
  }
}

// ---------------- GEMM2: Ob[pos] = gate*(H@Wc), BM=256 BN=128, 2 blocks/CU --
// 512 thr, 8 waves (4m x 2n, 64x64 each), acc[4][4]=64 f32/thread, LDS 48KB.
__launch_bounds__(512, 4)
__global__ void gemm2_k(const bf16* __restrict__ Hb, const bf16* __restrict__ wct,
                        const int* __restrict__ cnt, const int* __restrict__ eoff,
                        const float* __restrict__ rowgate, bf16* __restrict__ Ob) {
  int id = blockIdx.x;
  int nid = (id & 7) * 128 + (id >> 3);       // XCD swizzle (1024 % 8 == 0)
  int e = nid >> 6, rem = nid & 63;           // 8 mt(256) x 8 nt(128)
  int m0 = (rem >> 3) << 8;
  int n0 = (rem & 7) << 7;
  int n_e = cnt[e];
  if (m0 >= n_e) return;
  int base = eoff[e];

  __shared__ __align__(16) bf16 sA[2][256 * BK];   // 32KB
  __shared__ __align__(16) bf16 sB[2][128 * BK];   // 16KB

  int tid = threadIdx.x;
  int lane = tid & 63;
  int w = tid >> 6;
  int wr = (w >> 1) << 6;                     // 0,64,128,192
  int wc = (w & 1) << 6;                      // 0,64

  int srow = tid >> 2;                        // 0..127
  int kc = (((tid & 3) ^ ((tid >> 3) & 3)) << 3);

  const bf16 *ag0, *ag1;
  {
    int gi0 = base + m0 + srow;               // H rows slot-contiguous
    int gi1 = base + m0 + 128 + srow;
    gi0 = gi0 < NSLOT ? gi0 : NSLOT - 1;
    gi1 = gi1 < NSLOT ? gi1 : NSLOT - 1;
    ag0 = Hb + ((size_t)gi0 << 10) + kc;
    ag1 = Hb + ((size_t)gi1 << 10) + kc;
  }
  const bf16* bg = wct + ((size_t)e * EMB + n0 + srow) * HID + kc;   // 128 B-rows

  char* lA = (char*)sA + w * 1024;
  char* lB = (char*)sB + w * 1024;

#define G2STAGE(k0, b) do {                                                  \
    char* _A = lA + (b) * 16384; char* _B = lB + (b) * 8192;                 \
    GLOAD16(ag0 + (k0), _A);                                                 \
    GLOAD16(ag1 + (k0), _A + 8192);                                          \
    GLOAD16(bg + (k0), _B);                                                  \
  } while (0)

  f32x4 acc[4][4] = {};

  int chr = ((lane >> 4) ^ ((lane >> 1) & 3)) << 3;
  int ra = (wr + (lane & 15)) * BK + chr;
  int rb = (wc + (lane & 15)) * BK + chr;

  G2STAGE(0, 0);
  for (int t = 0; t < HID / BK; t++) {
    int cur = t & 1;
    if (t < HID / BK - 1) {
      G2STAGE((t + 1) * BK, cur ^ 1);         // keep next tile's 3 loads in flight
      VMW(3);
    } else {
      VMW(0);
    }
    __builtin_amdgcn_s_barrier();

    bf16x8 af[4], bfr[4];
#pragma unroll
    for (int m = 0; m < 4; m++) af[m] = *(const bf16x8*)&sA[cur][ra + m * 16 * BK];
#pragma unroll
    for (int n = 0; n < 4; n++) bfr[n] = *(const bf16x8*)&sB[cur][rb + n * 16 * BK];
#pragma unroll
    for (int m = 0; m < 4; m++)
#pragma unroll
      for (int n = 0; n < 4; n++)
        acc[m][n] = __builtin_amdgcn_mfma_f32_16x16x32_bf16(af[m], bfr[n], acc[m][n], 0, 0, 0);
    __builtin_amdgcn_s_barrier();
  }
#undef G2STAGE

  int rf = wr + ((lane >> 4) << 2);
  int cf = n0 + wc + (lane & 15);
#pragma unroll
  for (int m = 0; m < 4; m++) {
#pragma unroll
    for (int b = 0; b < 4; b++) {
      int gr = m0 + rf + m * 16 + b;
      if (gr < n_e) {
        int idx = base + gr;
        float g = rowgate[idx];
        bf16* orow = Ob + ((size_t)idx << 10) + cf;
#pragma unroll
        for (int n = 0; n < 4; n++)
          orow[n * 16] = (bf16)(g * acc[m][n][b]);
      }
    }
  }
}

// ---------------- combine: out[t] = Ob[posof[2t]] + Ob[posof[2t+1]] --------
__global__ void combine_k(const bf16* __restrict__ Ob, const int* __restrict__ posof,
                          float* __restrict__ out) {
  int t = blockIdx.x;
  int c = threadIdx.x << 2;
  int p1 = posof[2 * t], p2 = posof[2 * t + 1];
  bf16x4 a = *(const bf16x4*)&Ob[((size_t)p1 << 10) + c];
  bf16x4 b = *(const bf16x4*)&Ob[((size_t)p2 << 10) + c];
  float4 o;
  o.x = (float)a[0] + (float)b[0];
  o.y = (float)a[1] + (float)b[1];
  o.z = (float)a[2] + (float)b[2];
  o.w = (float)a[3] + (float)b[3];
  *(float4*)&out[((size_t)t << 10) + c] = o;
}

extern "C" void kernel_launch(void* const* d_in, const int* in_sizes, int n_in,
                              void* d_out, int out_size, void* d_ws, size_t ws_size,
                              hipStream_t stream) {
  const float* x  = (const float*)d_in[0];
  const float* wg = (const float*)d_in[1];
  const float* w1 = (const float*)d_in[2];
  const float* w2 = (const float*)d_in[3];
  const float* wc = (const float*)d_in[4];
  float* out = (float*)d_out;

  const size_t WELEM = (size_t)NE << 20;
  bf16* w1t  = (bf16*)d_ws;                        // [E][HID][EMB] bf16
  bf16* w2t  = w1t + WELEM;                        // [E][HID][EMB]
  bf16* wct  = w2t + WELEM;                        // [E][EMB][HID]
  bf16* xb   = wct + WELEM;                        // [NTOK][1024]
  bf16* Hb   = xb + ((size_t)NTOK << 10);          // [NSLOT][1024]
  int* cnt      = (int*)(Hb + ((size_t)NSLOT << 10));
  int* eoff     = cnt + 16;
  int* blockcnt = eoff + 16;                       // [64][16]
  int* blockoff = blockcnt + 64 * 16;              // [64][16]
  int* tokexp   = blockoff + 64 * 16;              // [NSLOT]
  float* tokgate = (float*)(tokexp + NSLOT);
  int* rowtok    = (int*)(tokgate + NSLOT);
  float* rowgate = (float*)(rowtok + NSLOT);
  int* posof     = (int*)(rowgate + NSLOT);        // [NSLOT]
  float* wgT     = (float*)(posof + NSLOT);        // [16][1024] fp32
  // Ob aliases w1t: w1t/w2t dead after gemm1 (same-stream kernels serialize)
  bf16* Ob = w1t;                                  // [NSLOT][1024] bf16 (= 32 MB)

  wgT_k<<<64, 256, 0, stream>>>(wg, wgT);
  prep_k<<<7168, 512, 0, stream>>>(w1, w2, wc, w1t, w2t, wct, x, wgT, xb, tokexp, tokgate);
  hist_k<<<NSLOT / 256, 256, 0, stream>>>(tokexp, blockcnt);
  scan_k<<<1, 64, 0, stream>>>(blockcnt, cnt, eoff, blockoff);
  assign_k<<<NSLOT / 256, 256, 0, stream>>>(tokexp, tokgate, blockoff, rowtok, rowgate, posof);
  gemm1_k<<<2048, 256, 0, stream>>>(xb, w1t, w2t, cnt, eoff, rowtok, Hb);
  gemm2_k<<<1024, 512, 0, stream>>>(Hb, wct, cnt, eoff, rowgate, Ob);
  combine_k<<<NTOK, 256, 0, stream>>>(Ob, posof, out);
}